// Round 1
// 195.927 us; speedup vs baseline: 1.0446x; 1.0446x over previous
//
#include <hip/hip_runtime.h>

// DeQuantizer: 4-bit GPTQ-style weight dequantization.
// qweight: int32 [K/8, N], qzeros: int32 [G, N/8], scales: f32 [G, N],
// g_idx: int32 [K] (sorted). out: f32 [K, N].
// out[k][n] = scales[g][n] * (((qw[k/8][n] >> 4*(k%8)) & 15) - ((qz[g][n/8] >> 4*(n%8)) & 15))
// with g = g_idx[k].
//
// Structure (this round): fully flattened. One block per (column-chunk, k-pack):
// grid (11, 512). Each block is straight-line: one iv4 qweight load, dequant,
// 8 fv4 stores (one per row of the pack), end. No loop-carried prefetch =>
// no vmcnt coupling between the store train and a subsequent load, so store
// completion is only waited on at end-of-wave and overlaps across the 8
// resident blocks/CU (32 waves/CU with __launch_bounds__(256, 8)).

#define NN 11008
#define NPACK (NN / 8)   // 1376
#define KPACKS 512       // 4096 / 8
#define NCHUNKS 11       // ceil(11008 / 1024)

typedef int   iv4 __attribute__((ext_vector_type(4)));
typedef float fv4 __attribute__((ext_vector_type(4)));

__global__ __launch_bounds__(256, 8) void dequant_kernel(
    const int* __restrict__ qweight,   // [512, N]
    const int* __restrict__ qzeros,    // [32, 1376]
    const float* __restrict__ scales,  // [32, N]
    const int* __restrict__ g_idx,     // [K]
    float* __restrict__ out)           // [K, N]
{
    const int kp = blockIdx.y;                      // rows kp*8 .. kp*8+7
    const int n  = blockIdx.x * 1024 + threadIdx.x * 4;  // 4 columns per thread
    if (n >= NN) return;                            // only ragged in chunk 10

    // packed weights for this thread's 4 columns (read exactly once globally)
    const iv4 q = __builtin_nontemporal_load(
        reinterpret_cast<const iv4*>(&qweight[(size_t)kp * NN + n]));

    // group ids for this pack's 8 rows (block-uniform -> scalar loads)
    int gs[8];
    #pragma unroll
    for (int j = 0; j < 8; ++j) gs[j] = g_idx[kp * 8 + j];
    const int g0 = gs[0];
    // g_idx is sorted, so g0==g7 implies all 8 rows share one group (~94%)
    const bool uniform = (g0 == gs[7]);

    float* outp = &out[(size_t)(kp * 8) * NN + n];
    const int zsh = (n & 4) * 4;    // cols n..n+3 -> nibbles of the zero word
    const int zw  = n >> 3;

    if (uniform) {
        const int zq = qzeros[g0 * NPACK + zw] >> zsh;
        const fv4 s  = *reinterpret_cast<const fv4*>(&scales[g0 * NN + n]);
        const float cx = -s.x * (float)((zq      ) & 15);
        const float cy = -s.y * (float)((zq >>  4) & 15);
        const float cz = -s.z * (float)((zq >>  8) & 15);
        const float cw = -s.w * (float)((zq >> 12) & 15);

        #pragma unroll
        for (int j = 0; j < 8; ++j) {
            const int sh = 4 * j;
            fv4 o;
            o.x = fmaf(s.x, (float)((q.x >> sh) & 15), cx);
            o.y = fmaf(s.y, (float)((q.y >> sh) & 15), cy);
            o.z = fmaf(s.z, (float)((q.z >> sh) & 15), cz);
            o.w = fmaf(s.w, (float)((q.w >> sh) & 15), cw);
            *reinterpret_cast<fv4*>(outp + (size_t)j * NN) = o;
        }
    } else {
        #pragma unroll
        for (int j = 0; j < 8; ++j) {
            const int g  = gs[j];
            const int zq = qzeros[g * NPACK + zw] >> zsh;
            const fv4 s  = *reinterpret_cast<const fv4*>(&scales[g * NN + n]);
            const int sh = 4 * j;
            fv4 o;
            o.x = s.x * ((float)((q.x >> sh) & 15) - (float)((zq      ) & 15));
            o.y = s.y * ((float)((q.y >> sh) & 15) - (float)((zq >>  4) & 15));
            o.z = s.z * ((float)((q.z >> sh) & 15) - (float)((zq >>  8) & 15));
            o.w = s.w * ((float)((q.w >> sh) & 15) - (float)((zq >> 12) & 15));
            *reinterpret_cast<fv4*>(outp + (size_t)j * NN) = o;
        }
    }
}

extern "C" void kernel_launch(void* const* d_in, const int* in_sizes, int n_in,
                              void* d_out, int out_size, void* d_ws, size_t ws_size,
                              hipStream_t stream) {
    const int*   qweight = (const int*)d_in[0];
    const int*   qzeros  = (const int*)d_in[1];
    const float* scales  = (const float*)d_in[2];
    const int*   g_idx   = (const int*)d_in[3];
    float*       out     = (float*)d_out;

    dim3 block(256);
    dim3 grid(NCHUNKS, KPACKS);   // (11, 512) = 5632 blocks, 8 resident blocks/CU
    dequant_kernel<<<grid, block, 0, stream>>>(qweight, qzeros, scales, g_idx, out);
}